// Round 6
// baseline (270.457 us; speedup 1.0000x reference)
//
#include <hip/hip_runtime.h>
#include <hip/hip_bf16.h>
#include <cstdint>
#include <cstddef>

#define P_ 256
#define L_ 6
#define D_ 300
#define J_ 3072   // P*2*L
#define N_ 4096
#define H_ 256
#define C_ 5
#define KP 320    // K padded to multiple of 32
#define KSTEPS 10 // KP/32
#define NCH 256   // time chunks
#define CS 16     // steps per chunk: NCH*CS == N_
#define SLOTS 32  // compose slots per p
#define PPB 8     // patterns per compose block
#define NBLK 256  // tail grid (must equal NCH)

#define SLS 0.62245933120185459f  // sigmoid(0.5)

typedef __attribute__((ext_vector_type(8))) short short8v;  // 8 bf16 (4 VGPRs)
typedef __attribute__((ext_vector_type(4))) float f32x4;

__device__ __forceinline__ float sigmoidf_(float x) { return 1.0f / (1.0f + __expf(-x)); }
__device__ __forceinline__ float bl_(unsigned u) { return __uint_as_float(u << 16); }
__device__ __forceinline__ float bh_(unsigned u) { return __uint_as_float(u & 0xffff0000u); }

// ---------------------------------------------------------------------------
// Prep: gather emb[doc] -> X bf16 [N_][KP]; diags -> Bb bf16 [J_][KP].
// Also zeroes the grid-barrier counter used by tail_all.
// ---------------------------------------------------------------------------
__global__ __launch_bounds__(256) void prep_XB(
    const int* __restrict__ doc, const float* __restrict__ emb,
    const float* __restrict__ diags,
    __hip_bfloat16* __restrict__ X, __hip_bfloat16* __restrict__ Bb,
    int* __restrict__ bar)
{
    const int i = blockIdx.x * 256 + threadIdx.x;
    if (i == 0) bar[0] = 0;   // barrier arrival counter (gen cell needs no init)
    const int NX = N_ * KP;
    if (i < NX) {
        const int n = i / KP, k = i - n * KP;
        float v = (k < D_) ? emb[(size_t)doc[n] * D_ + k] : 0.0f;
        X[i] = __float2bfloat16(v);
    } else {
        const int ii = i - NX;
        const int j = ii / KP, k = ii - j * KP;
        float v = (k < D_) ? diags[(size_t)j * D_ + k] : 0.0f;
        Bb[ii] = __float2bfloat16(v);
    }
}

// ---------------------------------------------------------------------------
// Kernel 2: T = sigmoid(X @ Bb^T + bias) -> bf16 T. (R3's 2-phase 128x128,
// fastest measured variant: ~18 us implied.)
// ---------------------------------------------------------------------------
__global__ __launch_bounds__(256) void gemm_mfma(
    const __hip_bfloat16* __restrict__ X, const __hip_bfloat16* __restrict__ Bb,
    const float* __restrict__ bias, __hip_bfloat16* __restrict__ T)
{
    __shared__ __hip_bfloat16 As[2][128 * 32];
    __shared__ __hip_bfloat16 Bs[2][128 * 32];

    const int tid  = threadIdx.x;
    const int lane = tid & 63;
    const int w    = tid >> 6;          // wave 0..3
    const int wr   = w >> 1, wc = w & 1;

    // XCD-aware bijective swizzle: nwg = 768 = 8 * 96
    const int bid = blockIdx.x;
    const int swz = (bid & 7) * 96 + (bid >> 3);
    const int bx  = swz % 24, by = swz / 24;   // 24 j-tiles, 32 m-tiles
    const int m0  = by * 128;
    const int j0  = bx * 128;

    const int srow = w * 32 + (lane >> 2);   // + q*16
    const int scol = (lane & 3) * 8;

    f32x4 acc[4][4];
    #pragma unroll
    for (int m = 0; m < 4; ++m)
        #pragma unroll
        for (int n = 0; n < 4; ++n)
            acc[m][n] = (f32x4){0.f, 0.f, 0.f, 0.f};

    const int fr = lane & 15;
    const int kg = (lane >> 4) * 8;

    auto stage = [&](int kt, int b) {
        const int k0 = kt * 32;
        #pragma unroll
        for (int q = 0; q < 2; ++q) {
            const __hip_bfloat16* ga = X + (size_t)(m0 + srow + q * 16) * KP + k0 + scol;
            __builtin_amdgcn_global_load_lds(
                (const __attribute__((address_space(1))) unsigned*)ga,
                (__attribute__((address_space(3))) unsigned*)(&As[b][(w * 2 + q) * 512]),
                16, 0, 0);
            const __hip_bfloat16* gb = Bb + (size_t)(j0 + srow + q * 16) * KP + k0 + scol;
            __builtin_amdgcn_global_load_lds(
                (const __attribute__((address_space(1))) unsigned*)gb,
                (__attribute__((address_space(3))) unsigned*)(&Bs[b][(w * 2 + q) * 512]),
                16, 0, 0);
        }
    };

    stage(0, 0);
    __syncthreads();

    int buf = 0;
    for (int kt = 0; kt < KSTEPS; ++kt) {
        if (kt + 1 < KSTEPS) stage(kt + 1, buf ^ 1);

        short8v a[4], b[4];
        #pragma unroll
        for (int m = 0; m < 4; ++m)
            a[m] = *(const short8v*)(&As[buf][(wr * 64 + m * 16 + fr) * 32 + kg]);
        #pragma unroll
        for (int n = 0; n < 4; ++n)
            b[n] = *(const short8v*)(&Bs[buf][(wc * 64 + n * 16 + fr) * 32 + kg]);
        #pragma unroll
        for (int m = 0; m < 4; ++m)
            #pragma unroll
            for (int n = 0; n < 4; ++n)
                acc[m][n] = __builtin_amdgcn_mfma_f32_16x16x32_bf16(a[m], b[n], acc[m][n], 0, 0, 0);

        __syncthreads();
        buf ^= 1;
    }

    #pragma unroll
    for (int n = 0; n < 4; ++n) {
        const int j = j0 + wc * 64 + n * 16 + fr;
        const float bj = bias[j];
        #pragma unroll
        for (int m = 0; m < 4; ++m) {
            const int rbase = m0 + wr * 64 + m * 16 + (lane >> 4) * 4;
            #pragma unroll
            for (int r = 0; r < 4; ++r) {
                float v = acc[m][n][r] + bj;
                T[(size_t)(rbase + r) * J_ + j] = __float2bfloat16(sigmoidf_(v));
            }
        }
    }
}

// ---------------------------------------------------------------------------
// Affine-map compose: N = C o R (apply R first, then C). 7x7 maps, flat q=j*7+i.
// ---------------------------------------------------------------------------
__device__ __forceinline__ void compose_maps(const float* C, const float* R, float* N)
{
    #pragma unroll
    for (int j = 0; j < 7; ++j) {
        #pragma unroll
        for (int i = 0; i < 6; ++i) {
            float a = (j == 6) ? C[42 + i] : 0.0f;
            #pragma unroll
            for (int u = 0; u < 6; ++u) a = fmaf(C[u * 7 + i], R[j * 7 + u], a);
            N[j * 7 + i] = a;
        }
        float sa = R[j * 7 + 6] + ((j == 6) ? C[48] : 0.0f);
        #pragma unroll
        for (int u = 0; u < 6; ++u) sa = fmaf(C[u * 7 + 6], R[j * 7 + u], sa);
        N[j * 7 + 6] = sa;
    }
}

// ---------------------------------------------------------------------------
// Device-scope grid barrier. All NBLK blocks co-resident by construction
// (256 blocks, >=2 blocks/CU capacity). Self-restoring: cnt returns to 0.
// ---------------------------------------------------------------------------
__device__ __forceinline__ void grid_barrier(int* cnt, int* gen, int nb)
{
    __syncthreads();
    if (threadIdx.x == 0) {
        __threadfence();
        int g = __hip_atomic_load(gen, __ATOMIC_ACQUIRE, __HIP_MEMORY_SCOPE_AGENT);
        int v = __hip_atomic_fetch_add(cnt, 1, __ATOMIC_ACQ_REL, __HIP_MEMORY_SCOPE_AGENT);
        if (v == nb - 1) {
            __hip_atomic_store(cnt, 0, __ATOMIC_RELAXED, __HIP_MEMORY_SCOPE_AGENT);
            __hip_atomic_fetch_add(gen, 1, __ATOMIC_ACQ_REL, __HIP_MEMORY_SCOPE_AGENT);
        } else {
            while (__hip_atomic_load(gen, __ATOMIC_ACQUIRE, __HIP_MEMORY_SCOPE_AGENT) == g)
                __builtin_amdgcn_s_sleep(8);
        }
    }
    __syncthreads();
}

// ---------------------------------------------------------------------------
// Kernel 3 (fused tail): P1 scan (block c: chunk map of CS steps) ->
// barrier -> P2 compose tree (32 blocks: 8 serial + 5-level LDS tree) ->
// barrier -> P3 MLP (block 0).
// ---------------------------------------------------------------------------
__global__ __launch_bounds__(256) void tail_all(
    const __hip_bfloat16* __restrict__ Tb, const float* __restrict__ epsilon,
    float* __restrict__ G1, float* __restrict__ scores, int* bar,
    const float* __restrict__ w0, const float* __restrict__ b0,
    const float* __restrict__ w1, const float* __restrict__ b1,
    const float* __restrict__ w2, const float* __restrict__ b2,
    float* __restrict__ out)
{
    __shared__ float lds[SLOTS * PPB * 49];   // 50176 B; reused by P3
    const int tid = threadIdx.x;
    const int bid = blockIdx.x;

    // ---------------- P1: per (chunk=bid, pattern=tid) affine map ----------
    {
        const int c = bid, p = tid;
        float ep[5];
        #pragma unroll
        for (int l = 0; l < 5; ++l)
            ep[l] = SLS * (1.0f / (1.0f + __expf(-epsilon[p * 5 + l])));

        float hc[7][6], sc[7];
        #pragma unroll
        for (int j = 0; j < 7; ++j) {
            sc[j] = 0.0f;
            #pragma unroll
            for (int i = 0; i < 6; ++i) hc[j][i] = (i == j) ? 1.0f : 0.0f;
        }

        const int t0 = c * CS;
        #pragma unroll 4
        for (int tt = 0; tt < CS; ++tt) {
            const int t = t0 + tt;
            const uint2* tp = (const uint2*)((const unsigned short*)Tb + (size_t)t * J_ + p * 12);
            uint2 u0 = tp[0], u1 = tp[1], u2 = tp[2];
            float T0[6] = { bl_(u0.x), bh_(u0.x), bl_(u0.y), bh_(u0.y), bl_(u1.x), bh_(u1.x) };
            float T1[6] = { bl_(u1.y), bh_(u1.y), bl_(u2.x), bh_(u2.x), bl_(u2.y), bh_(u2.y) };
            float sT0[6];
            #pragma unroll
            for (int l = 0; l < 6; ++l) sT0[l] = SLS * T0[l];

            #pragma unroll
            for (int j = 0; j < 7; ++j) {
                float m[6];
                m[0] = hc[j][0] * sT0[0];
                #pragma unroll
                for (int i = 1; i < 6; ++i)
                    m[i] = fmaf(hc[j][i - 1], T1[i - 1], hc[j][i] * sT0[i]);
                hc[j][0] = m[0] + ((j == 6) ? 1.0f : 0.0f);
                #pragma unroll
                for (int i = 1; i < 6; ++i)
                    hc[j][i] = fmaf(m[i - 1], ep[i - 1], m[i]);
                sc[j] += hc[j][5];
            }
        }

        #pragma unroll
        for (int j = 0; j < 7; ++j) {
            #pragma unroll
            for (int i = 0; i < 6; ++i)
                G1[((size_t)c * 49 + j * 7 + i) * P_ + p] = hc[j][i];
            G1[((size_t)c * 49 + j * 7 + 6) * P_ + p] = sc[j];
        }
    }

    grid_barrier(bar, bar + 1, NBLK);

    // ---------------- P2: compose 256 maps -> scores (blocks 0..31) --------
    if (bid < P_ / PPB) {
        const int pl = tid & (PPB - 1);
        const int s  = tid >> 3;            // slot 0..31
        const int p  = bid * PPB + pl;

        float R[49], Cm[49], Nn[49];
        const int c0 = s * (NCH / SLOTS);   // 8 chunks per slot
        #pragma unroll
        for (int q = 0; q < 49; ++q) R[q] = G1[((size_t)c0 * 49 + q) * P_ + p];
        for (int i = 1; i < NCH / SLOTS; ++i) {
            const int c = c0 + i;
            #pragma unroll
            for (int q = 0; q < 49; ++q) Cm[q] = G1[((size_t)c * 49 + q) * P_ + p];
            compose_maps(Cm, R, Nn);
            #pragma unroll
            for (int q = 0; q < 49; ++q) R[q] = Nn[q];
        }
        #pragma unroll
        for (int q = 0; q < 49; ++q) lds[tid * 49 + q] = R[q];

        // tree over slots, pairing (2s, 2s+1): result = M_{2s+1} o M_{2s}
        for (int act = SLOTS / 2; act >= 1; act >>= 1) {
            __syncthreads();
            if (s < act) {
                const float* Rm = &lds[((2 * s) * PPB + pl) * 49];
                const float* Cp = &lds[((2 * s + 1) * PPB + pl) * 49];
                compose_maps(Cp, Rm, Nn);
            }
            __syncthreads();
            if (s < act) {
                #pragma unroll
                for (int q = 0; q < 49; ++q) lds[(s * PPB + pl) * 49 + q] = Nn[q];
            }
        }
        __syncthreads();
        // apply to (h0=e0, s=0): score = M[col0].s + M[col6].s = q6 + q48
        if (s == 0) scores[p] = lds[pl * 49 + 6] + lds[pl * 49 + 48];
    }

    grid_barrier(bar, bar + 1, NBLK);

    // ---------------- P3: MLP head (block 0) -------------------------------
    if (bid == 0) {
        float* s0 = lds;
        float* z0 = lds + 256;
        float* z1 = lds + 512;

        s0[tid] = scores[tid];
        __syncthreads();

        float acc = b0[tid];
        {
            const float4* wr = (const float4*)(w0 + (size_t)tid * P_);
            #pragma unroll 4
            for (int q = 0; q < P_ / 4; ++q) {
                float4 w = wr[q];
                acc = fmaf(w.x, s0[q * 4 + 0], acc);
                acc = fmaf(w.y, s0[q * 4 + 1], acc);
                acc = fmaf(w.z, s0[q * 4 + 2], acc);
                acc = fmaf(w.w, s0[q * 4 + 3], acc);
            }
        }
        z0[tid] = fmaxf(acc, 0.0f);
        __syncthreads();

        acc = b1[tid];
        {
            const float4* wr = (const float4*)(w1 + (size_t)tid * H_);
            #pragma unroll 4
            for (int q = 0; q < H_ / 4; ++q) {
                float4 w = wr[q];
                acc = fmaf(w.x, z0[q * 4 + 0], acc);
                acc = fmaf(w.y, z0[q * 4 + 1], acc);
                acc = fmaf(w.z, z0[q * 4 + 2], acc);
                acc = fmaf(w.w, z0[q * 4 + 3], acc);
            }
        }
        z1[tid] = fmaxf(acc, 0.0f);
        __syncthreads();

        if (tid < C_) {
            float o = b2[tid];
            const float* wr = w2 + (size_t)tid * H_;
            for (int hh = 0; hh < H_; ++hh) o = fmaf(wr[hh], z1[hh], o);
            out[tid] = o;
        }
    }
}

// ---------------------------------------------------------------------------
extern "C" void kernel_launch(void* const* d_in, const int* in_sizes, int n_in,
                              void* d_out, int out_size, void* d_ws, size_t ws_size,
                              hipStream_t stream)
{
    const int*   doc     = (const int*)d_in[0];
    const float* emb     = (const float*)d_in[1];
    const float* diags   = (const float*)d_in[2];
    const float* bias    = (const float*)d_in[3];
    const float* epsilon = (const float*)d_in[4];
    const float* w0      = (const float*)d_in[5];
    const float* b0      = (const float*)d_in[6];
    const float* w1      = (const float*)d_in[7];
    const float* b1      = (const float*)d_in[8];
    const float* w2      = (const float*)d_in[9];
    const float* b2      = (const float*)d_in[10];
    float* out = (float*)d_out;

    // Workspace (~42.7 MB)
    float* G1     = (float*)d_ws;                       // NCH*49*256 fp32 (12.85 MB)
    float* scores = G1 + (size_t)NCH * 49 * P_;         // 256 floats
    int*   bar    = (int*)(scores + P_);                // 2 ints (+pad to 16B)
    __hip_bfloat16* Tb = (__hip_bfloat16*)(bar + 4);    // N_*J_ bf16 (25.2 MB)
    __hip_bfloat16* X  = Tb + (size_t)N_ * J_;          // N_*KP bf16 ( 2.6 MB)
    __hip_bfloat16* Bb = X  + (size_t)N_ * KP;          // J_*KP bf16 ( 2.0 MB)

    prep_XB<<<(N_ * KP + J_ * KP) / 256, 256, 0, stream>>>(doc, emb, diags, X, Bb, bar);
    gemm_mfma<<<(J_ / 128) * (N_ / 128), 256, 0, stream>>>(X, Bb, bias, Tb);
    tail_all<<<NBLK, 256, 0, stream>>>(Tb, epsilon, G1, scores, bar,
                                       w0, b0, w1, b1, w2, b2, out);
}

// Round 7
// 143.454 us; speedup vs baseline: 1.8853x; 1.8853x over previous
//
#include <hip/hip_runtime.h>
#include <hip/hip_bf16.h>
#include <cstdint>
#include <cstddef>

#define P_ 256
#define L_ 6
#define D_ 300
#define J_ 3072   // P*2*L
#define N_ 4096
#define H_ 256
#define C_ 5
#define KP 320    // K padded to multiple of 32
#define KSTEPS 10 // KP/32
#define NCH 256   // time chunks
#define CS 16     // steps per chunk: NCH*CS == N_
#define SLOTS 32  // compose slots per p
#define PPB 8     // patterns per compose block
#define NBLK 256  // tail grid (must equal NCH)

#define SLS 0.62245933120185459f  // sigmoid(0.5)

typedef __attribute__((ext_vector_type(8))) short short8v;  // 8 bf16 (4 VGPRs)
typedef __attribute__((ext_vector_type(4))) float f32x4;

__device__ __forceinline__ float sigmoidf_(float x) { return 1.0f / (1.0f + __expf(-x)); }
__device__ __forceinline__ float bl_(unsigned u) { return __uint_as_float(u << 16); }
__device__ __forceinline__ float bh_(unsigned u) { return __uint_as_float(u & 0xffff0000u); }

// ---------------------------------------------------------------------------
// Prep: gather emb[doc] -> X bf16 [N_][KP]; diags -> Bb bf16 [J_][KP].
// Also zeroes the grid-barrier counter used by tail_all.
// ---------------------------------------------------------------------------
__global__ __launch_bounds__(256) void prep_XB(
    const int* __restrict__ doc, const float* __restrict__ emb,
    const float* __restrict__ diags,
    __hip_bfloat16* __restrict__ X, __hip_bfloat16* __restrict__ Bb,
    int* __restrict__ bar)
{
    const int i = blockIdx.x * 256 + threadIdx.x;
    if (i == 0) bar[0] = 0;   // barrier arrival counter (gen cell needs no init)
    const int NX = N_ * KP;
    if (i < NX) {
        const int n = i / KP, k = i - n * KP;
        float v = (k < D_) ? emb[(size_t)doc[n] * D_ + k] : 0.0f;
        X[i] = __float2bfloat16(v);
    } else {
        const int ii = i - NX;
        const int j = ii / KP, k = ii - j * KP;
        float v = (k < D_) ? diags[(size_t)j * D_ + k] : 0.0f;
        Bb[ii] = __float2bfloat16(v);
    }
}

// ---------------------------------------------------------------------------
// Kernel 2: T = sigmoid(X @ Bb^T + bias) -> bf16 T. (R3's 2-phase 128x128.)
// ---------------------------------------------------------------------------
__global__ __launch_bounds__(256) void gemm_mfma(
    const __hip_bfloat16* __restrict__ X, const __hip_bfloat16* __restrict__ Bb,
    const float* __restrict__ bias, __hip_bfloat16* __restrict__ T)
{
    __shared__ __hip_bfloat16 As[2][128 * 32];
    __shared__ __hip_bfloat16 Bs[2][128 * 32];

    const int tid  = threadIdx.x;
    const int lane = tid & 63;
    const int w    = tid >> 6;          // wave 0..3
    const int wr   = w >> 1, wc = w & 1;

    // XCD-aware bijective swizzle: nwg = 768 = 8 * 96
    const int bid = blockIdx.x;
    const int swz = (bid & 7) * 96 + (bid >> 3);
    const int bx  = swz % 24, by = swz / 24;   // 24 j-tiles, 32 m-tiles
    const int m0  = by * 128;
    const int j0  = bx * 128;

    const int srow = w * 32 + (lane >> 2);   // + q*16
    const int scol = (lane & 3) * 8;

    f32x4 acc[4][4];
    #pragma unroll
    for (int m = 0; m < 4; ++m)
        #pragma unroll
        for (int n = 0; n < 4; ++n)
            acc[m][n] = (f32x4){0.f, 0.f, 0.f, 0.f};

    const int fr = lane & 15;
    const int kg = (lane >> 4) * 8;

    auto stage = [&](int kt, int b) {
        const int k0 = kt * 32;
        #pragma unroll
        for (int q = 0; q < 2; ++q) {
            const __hip_bfloat16* ga = X + (size_t)(m0 + srow + q * 16) * KP + k0 + scol;
            __builtin_amdgcn_global_load_lds(
                (const __attribute__((address_space(1))) unsigned*)ga,
                (__attribute__((address_space(3))) unsigned*)(&As[b][(w * 2 + q) * 512]),
                16, 0, 0);
            const __hip_bfloat16* gb = Bb + (size_t)(j0 + srow + q * 16) * KP + k0 + scol;
            __builtin_amdgcn_global_load_lds(
                (const __attribute__((address_space(1))) unsigned*)gb,
                (__attribute__((address_space(3))) unsigned*)(&Bs[b][(w * 2 + q) * 512]),
                16, 0, 0);
        }
    };

    stage(0, 0);
    __syncthreads();

    int buf = 0;
    for (int kt = 0; kt < KSTEPS; ++kt) {
        if (kt + 1 < KSTEPS) stage(kt + 1, buf ^ 1);

        short8v a[4], b[4];
        #pragma unroll
        for (int m = 0; m < 4; ++m)
            a[m] = *(const short8v*)(&As[buf][(wr * 64 + m * 16 + fr) * 32 + kg]);
        #pragma unroll
        for (int n = 0; n < 4; ++n)
            b[n] = *(const short8v*)(&Bs[buf][(wc * 64 + n * 16 + fr) * 32 + kg]);
        #pragma unroll
        for (int m = 0; m < 4; ++m)
            #pragma unroll
            for (int n = 0; n < 4; ++n)
                acc[m][n] = __builtin_amdgcn_mfma_f32_16x16x32_bf16(a[m], b[n], acc[m][n], 0, 0, 0);

        __syncthreads();
        buf ^= 1;
    }

    #pragma unroll
    for (int n = 0; n < 4; ++n) {
        const int j = j0 + wc * 64 + n * 16 + fr;
        const float bj = bias[j];
        #pragma unroll
        for (int m = 0; m < 4; ++m) {
            const int rbase = m0 + wr * 64 + m * 16 + (lane >> 4) * 4;
            #pragma unroll
            for (int r = 0; r < 4; ++r) {
                float v = acc[m][n][r] + bj;
                T[(size_t)(rbase + r) * J_ + j] = __float2bfloat16(sigmoidf_(v));
            }
        }
    }
}

// ---------------------------------------------------------------------------
// Affine-map compose: N = C o R (apply R first, then C). 7x7 maps, flat q=j*7+i.
// ---------------------------------------------------------------------------
__device__ __forceinline__ void compose_maps(const float* C, const float* R, float* N)
{
    #pragma unroll
    for (int j = 0; j < 7; ++j) {
        #pragma unroll
        for (int i = 0; i < 6; ++i) {
            float a = (j == 6) ? C[42 + i] : 0.0f;
            #pragma unroll
            for (int u = 0; u < 6; ++u) a = fmaf(C[u * 7 + i], R[j * 7 + u], a);
            N[j * 7 + i] = a;
        }
        float sa = R[j * 7 + 6] + ((j == 6) ? C[48] : 0.0f);
        #pragma unroll
        for (int u = 0; u < 6; ++u) sa = fmaf(C[u * 7 + 6], R[j * 7 + u], sa);
        N[j * 7 + 6] = sa;
    }
}

// ---------------------------------------------------------------------------
// Device-scope grid barrier, RELAXED spin.
// R6 lesson: an ACQUIRE agent-scope load in the spin loop emits an L2
// invalidate per poll on gfx950 (non-coherent XCD L2s) -> 255 pollers
// continuously nuke L2 chip-wide (262 us tail, 190 GB/s). Relaxed agent
// atomics bypass stale caches (read at the coherence point) WITHOUT the
// invalidate; the acquire is hoisted to ONE __threadfence() at exit.
// Self-restoring: cnt returns to 0 every call (graph-replay deterministic).
// ---------------------------------------------------------------------------
__device__ __forceinline__ void grid_barrier(int* cnt, int* gen, int nb)
{
    __syncthreads();
    if (threadIdx.x == 0) {
        __threadfence();   // release my phase's stores
        int g = __hip_atomic_load(gen, __ATOMIC_RELAXED, __HIP_MEMORY_SCOPE_AGENT);
        int v = __hip_atomic_fetch_add(cnt, 1, __ATOMIC_ACQ_REL, __HIP_MEMORY_SCOPE_AGENT);
        if (v == nb - 1) {
            __hip_atomic_store(cnt, 0, __ATOMIC_RELAXED, __HIP_MEMORY_SCOPE_AGENT);
            // RELEASE on gen orders the cnt reset before the flip is visible.
            __hip_atomic_fetch_add(gen, 1, __ATOMIC_ACQ_REL, __HIP_MEMORY_SCOPE_AGENT);
        } else {
            while (__hip_atomic_load(gen, __ATOMIC_RELAXED, __HIP_MEMORY_SCOPE_AGENT) == g)
                __builtin_amdgcn_s_sleep(8);
        }
        __threadfence();   // acquire: one invalidate, fresh view of others' data
    }
    __syncthreads();
}

// ---------------------------------------------------------------------------
// Kernel 3 (fused tail): P1 scan (block c: chunk map of CS steps) ->
// barrier -> P2 compose tree (32 blocks: 8 serial + 5-level LDS tree) ->
// barrier -> P3 MLP (block 0).
// ---------------------------------------------------------------------------
__global__ __launch_bounds__(256) void tail_all(
    const __hip_bfloat16* __restrict__ Tb, const float* __restrict__ epsilon,
    float* __restrict__ G1, float* __restrict__ scores, int* bar,
    const float* __restrict__ w0, const float* __restrict__ b0,
    const float* __restrict__ w1, const float* __restrict__ b1,
    const float* __restrict__ w2, const float* __restrict__ b2,
    float* __restrict__ out)
{
    __shared__ float lds[SLOTS * PPB * 49];   // 50176 B; reused by P3
    const int tid = threadIdx.x;
    const int bid = blockIdx.x;

    // ---------------- P1: per (chunk=bid, pattern=tid) affine map ----------
    {
        const int c = bid, p = tid;
        float ep[5];
        #pragma unroll
        for (int l = 0; l < 5; ++l)
            ep[l] = SLS * (1.0f / (1.0f + __expf(-epsilon[p * 5 + l])));

        float hc[7][6], sc[7];
        #pragma unroll
        for (int j = 0; j < 7; ++j) {
            sc[j] = 0.0f;
            #pragma unroll
            for (int i = 0; i < 6; ++i) hc[j][i] = (i == j) ? 1.0f : 0.0f;
        }

        const int t0 = c * CS;
        #pragma unroll 4
        for (int tt = 0; tt < CS; ++tt) {
            const int t = t0 + tt;
            const uint2* tp = (const uint2*)((const unsigned short*)Tb + (size_t)t * J_ + p * 12);
            uint2 u0 = tp[0], u1 = tp[1], u2 = tp[2];
            float T0[6] = { bl_(u0.x), bh_(u0.x), bl_(u0.y), bh_(u0.y), bl_(u1.x), bh_(u1.x) };
            float T1[6] = { bl_(u1.y), bh_(u1.y), bl_(u2.x), bh_(u2.x), bl_(u2.y), bh_(u2.y) };
            float sT0[6];
            #pragma unroll
            for (int l = 0; l < 6; ++l) sT0[l] = SLS * T0[l];

            #pragma unroll
            for (int j = 0; j < 7; ++j) {
                float m[6];
                m[0] = hc[j][0] * sT0[0];
                #pragma unroll
                for (int i = 1; i < 6; ++i)
                    m[i] = fmaf(hc[j][i - 1], T1[i - 1], hc[j][i] * sT0[i]);
                hc[j][0] = m[0] + ((j == 6) ? 1.0f : 0.0f);
                #pragma unroll
                for (int i = 1; i < 6; ++i)
                    hc[j][i] = fmaf(m[i - 1], ep[i - 1], m[i]);
                sc[j] += hc[j][5];
            }
        }

        #pragma unroll
        for (int j = 0; j < 7; ++j) {
            #pragma unroll
            for (int i = 0; i < 6; ++i)
                G1[((size_t)c * 49 + j * 7 + i) * P_ + p] = hc[j][i];
            G1[((size_t)c * 49 + j * 7 + 6) * P_ + p] = sc[j];
        }
    }

    grid_barrier(bar, bar + 1, NBLK);

    // ---------------- P2: compose 256 maps -> scores (blocks 0..31) --------
    if (bid < P_ / PPB) {
        const int pl = tid & (PPB - 1);
        const int s  = tid >> 3;            // slot 0..31
        const int p  = bid * PPB + pl;

        float R[49], Cm[49], Nn[49];
        const int c0 = s * (NCH / SLOTS);   // 8 chunks per slot
        #pragma unroll
        for (int q = 0; q < 49; ++q) R[q] = G1[((size_t)c0 * 49 + q) * P_ + p];
        for (int i = 1; i < NCH / SLOTS; ++i) {
            const int c = c0 + i;
            #pragma unroll
            for (int q = 0; q < 49; ++q) Cm[q] = G1[((size_t)c * 49 + q) * P_ + p];
            compose_maps(Cm, R, Nn);
            #pragma unroll
            for (int q = 0; q < 49; ++q) R[q] = Nn[q];
        }
        #pragma unroll
        for (int q = 0; q < 49; ++q) lds[tid * 49 + q] = R[q];

        // tree over slots, pairing (2s, 2s+1): result = M_{2s+1} o M_{2s}
        for (int act = SLOTS / 2; act >= 1; act >>= 1) {
            __syncthreads();
            if (s < act) {
                const float* Rm = &lds[((2 * s) * PPB + pl) * 49];
                const float* Cp = &lds[((2 * s + 1) * PPB + pl) * 49];
                compose_maps(Cp, Rm, Nn);
            }
            __syncthreads();
            if (s < act) {
                #pragma unroll
                for (int q = 0; q < 49; ++q) lds[(s * PPB + pl) * 49 + q] = Nn[q];
            }
        }
        __syncthreads();
        // apply to (h0=e0, s=0): score = M[col0].s + M[col6].s = q6 + q48
        if (s == 0) scores[p] = lds[pl * 49 + 6] + lds[pl * 49 + 48];
    }

    grid_barrier(bar, bar + 1, NBLK);

    // ---------------- P3: MLP head (block 0) -------------------------------
    if (bid == 0) {
        float* s0 = lds;
        float* z0 = lds + 256;
        float* z1 = lds + 512;

        s0[tid] = scores[tid];
        __syncthreads();

        float acc = b0[tid];
        {
            const float4* wr = (const float4*)(w0 + (size_t)tid * P_);
            #pragma unroll 4
            for (int q = 0; q < P_ / 4; ++q) {
                float4 w = wr[q];
                acc = fmaf(w.x, s0[q * 4 + 0], acc);
                acc = fmaf(w.y, s0[q * 4 + 1], acc);
                acc = fmaf(w.z, s0[q * 4 + 2], acc);
                acc = fmaf(w.w, s0[q * 4 + 3], acc);
            }
        }
        z0[tid] = fmaxf(acc, 0.0f);
        __syncthreads();

        acc = b1[tid];
        {
            const float4* wr = (const float4*)(w1 + (size_t)tid * H_);
            #pragma unroll 4
            for (int q = 0; q < H_ / 4; ++q) {
                float4 w = wr[q];
                acc = fmaf(w.x, z0[q * 4 + 0], acc);
                acc = fmaf(w.y, z0[q * 4 + 1], acc);
                acc = fmaf(w.z, z0[q * 4 + 2], acc);
                acc = fmaf(w.w, z0[q * 4 + 3], acc);
            }
        }
        z1[tid] = fmaxf(acc, 0.0f);
        __syncthreads();

        if (tid < C_) {
            float o = b2[tid];
            const float* wr = w2 + (size_t)tid * H_;
            for (int hh = 0; hh < H_; ++hh) o = fmaf(wr[hh], z1[hh], o);
            out[tid] = o;
        }
    }
}

// ---------------------------------------------------------------------------
extern "C" void kernel_launch(void* const* d_in, const int* in_sizes, int n_in,
                              void* d_out, int out_size, void* d_ws, size_t ws_size,
                              hipStream_t stream)
{
    const int*   doc     = (const int*)d_in[0];
    const float* emb     = (const float*)d_in[1];
    const float* diags   = (const float*)d_in[2];
    const float* bias    = (const float*)d_in[3];
    const float* epsilon = (const float*)d_in[4];
    const float* w0      = (const float*)d_in[5];
    const float* b0      = (const float*)d_in[6];
    const float* w1      = (const float*)d_in[7];
    const float* b1      = (const float*)d_in[8];
    const float* w2      = (const float*)d_in[9];
    const float* b2      = (const float*)d_in[10];
    float* out = (float*)d_out;

    // Workspace (~42.7 MB)
    float* G1     = (float*)d_ws;                       // NCH*49*256 fp32 (12.85 MB)
    float* scores = G1 + (size_t)NCH * 49 * P_;         // 256 floats
    int*   bar    = (int*)(scores + P_);                // 2 ints (+pad to 16B)
    __hip_bfloat16* Tb = (__hip_bfloat16*)(bar + 4);    // N_*J_ bf16 (25.2 MB)
    __hip_bfloat16* X  = Tb + (size_t)N_ * J_;          // N_*KP bf16 ( 2.6 MB)
    __hip_bfloat16* Bb = X  + (size_t)N_ * KP;          // J_*KP bf16 ( 2.0 MB)

    prep_XB<<<(N_ * KP + J_ * KP) / 256, 256, 0, stream>>>(doc, emb, diags, X, Bb, bar);
    gemm_mfma<<<(J_ / 128) * (N_ / 128), 256, 0, stream>>>(X, Bb, bias, Tb);
    tail_all<<<NBLK, 256, 0, stream>>>(Tb, epsilon, G1, scores, bar,
                                       w0, b0, w1, b1, w2, b2, out);
}

// Round 8
// 110.407 us; speedup vs baseline: 2.4496x; 1.2993x over previous
//
#include <hip/hip_runtime.h>
#include <hip/hip_bf16.h>
#include <cstdint>
#include <cstddef>

#define P_ 256
#define L_ 6
#define D_ 300
#define J_ 3072   // P*2*L
#define N_ 4096
#define H_ 256
#define C_ 5
#define KP 320    // K padded to multiple of 32
#define KSTEPS 10 // KP/32
#define NCH 256   // time chunks
#define CS 16     // steps per chunk: NCH*CS == N_
#define SLOTS 32  // compose slots per p
#define PPB 8     // patterns per compose block
#define NBLK 256  // tail grid (must equal NCH)

#define SLS 0.62245933120185459f  // sigmoid(0.5)

typedef __attribute__((ext_vector_type(8))) short short8v;  // 8 bf16 (4 VGPRs)
typedef __attribute__((ext_vector_type(4))) float f32x4;

__device__ __forceinline__ float sigmoidf_(float x) { return 1.0f / (1.0f + __expf(-x)); }
__device__ __forceinline__ float bl_(unsigned u) { return __uint_as_float(u << 16); }
__device__ __forceinline__ float bh_(unsigned u) { return __uint_as_float(u & 0xffff0000u); }

// RMW-based poll: executed at the coherence point (never served from a stale
// per-XCD L2 line like a plain load; no cache invalidate like an acquire load).
__device__ __forceinline__ int rmw_peek(int* p) {
    return __hip_atomic_fetch_add(p, 0, __ATOMIC_RELAXED, __HIP_MEMORY_SCOPE_AGENT);
}

// ---------------------------------------------------------------------------
// Prep: gather emb[doc] -> X bf16 [N_][KP]; diags -> Bb bf16 [J_][KP].
// Zeroes BOTH tail counters each call (graph-replay deterministic; visibility
// to tail_all guaranteed by kernel-boundary release).
// ---------------------------------------------------------------------------
__global__ __launch_bounds__(256) void prep_XB(
    const int* __restrict__ doc, const float* __restrict__ emb,
    const float* __restrict__ diags,
    __hip_bfloat16* __restrict__ X, __hip_bfloat16* __restrict__ Bb,
    int* __restrict__ bar)
{
    const int i = blockIdx.x * 256 + threadIdx.x;
    if (i == 0) { bar[0] = 0; bar[1] = 0; }
    const int NX = N_ * KP;
    if (i < NX) {
        const int n = i / KP, k = i - n * KP;
        float v = (k < D_) ? emb[(size_t)doc[n] * D_ + k] : 0.0f;
        X[i] = __float2bfloat16(v);
    } else {
        const int ii = i - NX;
        const int j = ii / KP, k = ii - j * KP;
        float v = (k < D_) ? diags[(size_t)j * D_ + k] : 0.0f;
        Bb[ii] = __float2bfloat16(v);
    }
}

// ---------------------------------------------------------------------------
// Kernel 2: T = sigmoid(X @ Bb^T + bias) -> bf16 T. (R3's 2-phase 128x128.)
// ---------------------------------------------------------------------------
__global__ __launch_bounds__(256) void gemm_mfma(
    const __hip_bfloat16* __restrict__ X, const __hip_bfloat16* __restrict__ Bb,
    const float* __restrict__ bias, __hip_bfloat16* __restrict__ T)
{
    __shared__ __hip_bfloat16 As[2][128 * 32];
    __shared__ __hip_bfloat16 Bs[2][128 * 32];

    const int tid  = threadIdx.x;
    const int lane = tid & 63;
    const int w    = tid >> 6;          // wave 0..3
    const int wr   = w >> 1, wc = w & 1;

    // XCD-aware bijective swizzle: nwg = 768 = 8 * 96
    const int bid = blockIdx.x;
    const int swz = (bid & 7) * 96 + (bid >> 3);
    const int bx  = swz % 24, by = swz / 24;   // 24 j-tiles, 32 m-tiles
    const int m0  = by * 128;
    const int j0  = bx * 128;

    const int srow = w * 32 + (lane >> 2);   // + q*16
    const int scol = (lane & 3) * 8;

    f32x4 acc[4][4];
    #pragma unroll
    for (int m = 0; m < 4; ++m)
        #pragma unroll
        for (int n = 0; n < 4; ++n)
            acc[m][n] = (f32x4){0.f, 0.f, 0.f, 0.f};

    const int fr = lane & 15;
    const int kg = (lane >> 4) * 8;

    auto stage = [&](int kt, int b) {
        const int k0 = kt * 32;
        #pragma unroll
        for (int q = 0; q < 2; ++q) {
            const __hip_bfloat16* ga = X + (size_t)(m0 + srow + q * 16) * KP + k0 + scol;
            __builtin_amdgcn_global_load_lds(
                (const __attribute__((address_space(1))) unsigned*)ga,
                (__attribute__((address_space(3))) unsigned*)(&As[b][(w * 2 + q) * 512]),
                16, 0, 0);
            const __hip_bfloat16* gb = Bb + (size_t)(j0 + srow + q * 16) * KP + k0 + scol;
            __builtin_amdgcn_global_load_lds(
                (const __attribute__((address_space(1))) unsigned*)gb,
                (__attribute__((address_space(3))) unsigned*)(&Bs[b][(w * 2 + q) * 512]),
                16, 0, 0);
        }
    };

    stage(0, 0);
    __syncthreads();

    int buf = 0;
    for (int kt = 0; kt < KSTEPS; ++kt) {
        if (kt + 1 < KSTEPS) stage(kt + 1, buf ^ 1);

        short8v a[4], b[4];
        #pragma unroll
        for (int m = 0; m < 4; ++m)
            a[m] = *(const short8v*)(&As[buf][(wr * 64 + m * 16 + fr) * 32 + kg]);
        #pragma unroll
        for (int n = 0; n < 4; ++n)
            b[n] = *(const short8v*)(&Bs[buf][(wc * 64 + n * 16 + fr) * 32 + kg]);
        #pragma unroll
        for (int m = 0; m < 4; ++m)
            #pragma unroll
            for (int n = 0; n < 4; ++n)
                acc[m][n] = __builtin_amdgcn_mfma_f32_16x16x32_bf16(a[m], b[n], acc[m][n], 0, 0, 0);

        __syncthreads();
        buf ^= 1;
    }

    #pragma unroll
    for (int n = 0; n < 4; ++n) {
        const int j = j0 + wc * 64 + n * 16 + fr;
        const float bj = bias[j];
        #pragma unroll
        for (int m = 0; m < 4; ++m) {
            const int rbase = m0 + wr * 64 + m * 16 + (lane >> 4) * 4;
            #pragma unroll
            for (int r = 0; r < 4; ++r) {
                float v = acc[m][n][r] + bj;
                T[(size_t)(rbase + r) * J_ + j] = __float2bfloat16(sigmoidf_(v));
            }
        }
    }
}

// ---------------------------------------------------------------------------
// Affine-map compose: N = C o R (apply R first, then C). 7x7 maps, flat q=j*7+i.
// ---------------------------------------------------------------------------
__device__ __forceinline__ void compose_maps(const float* C, const float* R, float* N)
{
    #pragma unroll
    for (int j = 0; j < 7; ++j) {
        #pragma unroll
        for (int i = 0; i < 6; ++i) {
            float a = (j == 6) ? C[42 + i] : 0.0f;
            #pragma unroll
            for (int u = 0; u < 6; ++u) a = fmaf(C[u * 7 + i], R[j * 7 + u], a);
            N[j * 7 + i] = a;
        }
        float sa = R[j * 7 + 6] + ((j == 6) ? C[48] : 0.0f);
        #pragma unroll
        for (int u = 0; u < 6; ++u) sa = fmaf(C[u * 7 + 6], R[j * 7 + u], sa);
        N[j * 7 + 6] = sa;
    }
}

// ---------------------------------------------------------------------------
// Kernel 3 (fused tail), producer/consumer sync via RMW polls:
//   P1 (all 256 blocks): chunk maps -> G1; fence; bar[0]++. Blocks >=32 EXIT.
//   P2 (blocks 0..31): poll bar[0]==256 (RMW), fence, compose -> scores;
//                      fence; bar[1]++. Blocks 1..31 EXIT.
//   P3 (block 0): poll bar[1]==32 (RMW), fence, MLP.
// No co-residency requirement: waiters (<=32 blocks) never block arrivers.
// ---------------------------------------------------------------------------
__global__ __launch_bounds__(256) void tail_all(
    const __hip_bfloat16* __restrict__ Tb, const float* __restrict__ epsilon,
    float* __restrict__ G1, float* __restrict__ scores, int* bar,
    const float* __restrict__ w0, const float* __restrict__ b0,
    const float* __restrict__ w1, const float* __restrict__ b1,
    const float* __restrict__ w2, const float* __restrict__ b2,
    float* __restrict__ out)
{
    __shared__ float lds[SLOTS * PPB * 49];   // 50176 B; reused by P3
    const int tid = threadIdx.x;
    const int bid = blockIdx.x;

    // ---------------- P1: per (chunk=bid, pattern=tid) affine map ----------
    {
        const int c = bid, p = tid;
        float ep[5];
        #pragma unroll
        for (int l = 0; l < 5; ++l)
            ep[l] = SLS * (1.0f / (1.0f + __expf(-epsilon[p * 5 + l])));

        float hc[7][6], sc[7];
        #pragma unroll
        for (int j = 0; j < 7; ++j) {
            sc[j] = 0.0f;
            #pragma unroll
            for (int i = 0; i < 6; ++i) hc[j][i] = (i == j) ? 1.0f : 0.0f;
        }

        const int t0 = c * CS;
        #pragma unroll 4
        for (int tt = 0; tt < CS; ++tt) {
            const int t = t0 + tt;
            const uint2* tp = (const uint2*)((const unsigned short*)Tb + (size_t)t * J_ + p * 12);
            uint2 u0 = tp[0], u1 = tp[1], u2 = tp[2];
            float T0[6] = { bl_(u0.x), bh_(u0.x), bl_(u0.y), bh_(u0.y), bl_(u1.x), bh_(u1.x) };
            float T1[6] = { bl_(u1.y), bh_(u1.y), bl_(u2.x), bh_(u2.x), bl_(u2.y), bh_(u2.y) };
            float sT0[6];
            #pragma unroll
            for (int l = 0; l < 6; ++l) sT0[l] = SLS * T0[l];

            #pragma unroll
            for (int j = 0; j < 7; ++j) {
                float m[6];
                m[0] = hc[j][0] * sT0[0];
                #pragma unroll
                for (int i = 1; i < 6; ++i)
                    m[i] = fmaf(hc[j][i - 1], T1[i - 1], hc[j][i] * sT0[i]);
                hc[j][0] = m[0] + ((j == 6) ? 1.0f : 0.0f);
                #pragma unroll
                for (int i = 1; i < 6; ++i)
                    hc[j][i] = fmaf(m[i - 1], ep[i - 1], m[i]);
                sc[j] += hc[j][5];
            }
        }

        #pragma unroll
        for (int j = 0; j < 7; ++j) {
            #pragma unroll
            for (int i = 0; i < 6; ++i)
                G1[((size_t)c * 49 + j * 7 + i) * P_ + p] = hc[j][i];
            G1[((size_t)c * 49 + j * 7 + 6) * P_ + p] = sc[j];
        }
    }

    __syncthreads();
    if (tid == 0) {
        __threadfence();   // release G1 stores to the coherence point
        __hip_atomic_fetch_add(bar, 1, __ATOMIC_RELEASE, __HIP_MEMORY_SCOPE_AGENT);
    }
    if (bid >= P_ / PPB) return;   // 224 blocks done — no spinners

    if (tid == 0) {
        while (rmw_peek(bar) < NBLK) __builtin_amdgcn_s_sleep(2);
        __threadfence();   // acquire: fresh view of all G1
    }
    __syncthreads();

    // ---------------- P2: compose 256 maps -> scores (blocks 0..31) --------
    {
        const int pl = tid & (PPB - 1);
        const int s  = tid >> 3;            // slot 0..31
        const int p  = bid * PPB + pl;

        float R[49], Cm[49], Nn[49];
        const int c0 = s * (NCH / SLOTS);   // 8 chunks per slot
        #pragma unroll
        for (int q = 0; q < 49; ++q) R[q] = G1[((size_t)c0 * 49 + q) * P_ + p];
        for (int i = 1; i < NCH / SLOTS; ++i) {
            const int c = c0 + i;
            #pragma unroll
            for (int q = 0; q < 49; ++q) Cm[q] = G1[((size_t)c * 49 + q) * P_ + p];
            compose_maps(Cm, R, Nn);
            #pragma unroll
            for (int q = 0; q < 49; ++q) R[q] = Nn[q];
        }
        #pragma unroll
        for (int q = 0; q < 49; ++q) lds[tid * 49 + q] = R[q];

        // tree over slots, pairing (2s, 2s+1): result = M_{2s+1} o M_{2s}
        for (int act = SLOTS / 2; act >= 1; act >>= 1) {
            __syncthreads();
            if (s < act) {
                const float* Rm = &lds[((2 * s) * PPB + pl) * 49];
                const float* Cp = &lds[((2 * s + 1) * PPB + pl) * 49];
                compose_maps(Cp, Rm, Nn);
            }
            __syncthreads();
            if (s < act) {
                #pragma unroll
                for (int q = 0; q < 49; ++q) lds[(s * PPB + pl) * 49 + q] = Nn[q];
            }
        }
        __syncthreads();
        // apply to (h0=e0, s=0): score = M[col0].s + M[col6].s = q6 + q48
        if (s == 0) scores[p] = lds[pl * 49 + 6] + lds[pl * 49 + 48];
    }

    __syncthreads();
    if (tid == 0) {
        __threadfence();
        __hip_atomic_fetch_add(bar + 1, 1, __ATOMIC_RELEASE, __HIP_MEMORY_SCOPE_AGENT);
    }
    if (bid != 0) return;   // 31 more blocks done

    if (tid == 0) {
        while (rmw_peek(bar + 1) < P_ / PPB) __builtin_amdgcn_s_sleep(2);
        __threadfence();
    }
    __syncthreads();

    // ---------------- P3: MLP head (block 0) -------------------------------
    {
        float* s0 = lds;
        float* z0 = lds + 256;
        float* z1 = lds + 512;

        s0[tid] = scores[tid];
        __syncthreads();

        float acc = b0[tid];
        {
            const float4* wr = (const float4*)(w0 + (size_t)tid * P_);
            #pragma unroll 4
            for (int q = 0; q < P_ / 4; ++q) {
                float4 w = wr[q];
                acc = fmaf(w.x, s0[q * 4 + 0], acc);
                acc = fmaf(w.y, s0[q * 4 + 1], acc);
                acc = fmaf(w.z, s0[q * 4 + 2], acc);
                acc = fmaf(w.w, s0[q * 4 + 3], acc);
            }
        }
        z0[tid] = fmaxf(acc, 0.0f);
        __syncthreads();

        acc = b1[tid];
        {
            const float4* wr = (const float4*)(w1 + (size_t)tid * H_);
            #pragma unroll 4
            for (int q = 0; q < H_ / 4; ++q) {
                float4 w = wr[q];
                acc = fmaf(w.x, z0[q * 4 + 0], acc);
                acc = fmaf(w.y, z0[q * 4 + 1], acc);
                acc = fmaf(w.z, z0[q * 4 + 2], acc);
                acc = fmaf(w.w, z0[q * 4 + 3], acc);
            }
        }
        z1[tid] = fmaxf(acc, 0.0f);
        __syncthreads();

        if (tid < C_) {
            float o = b2[tid];
            const float* wr = w2 + (size_t)tid * H_;
            for (int hh = 0; hh < H_; ++hh) o = fmaf(wr[hh], z1[hh], o);
            out[tid] = o;
        }
    }
}

// ---------------------------------------------------------------------------
extern "C" void kernel_launch(void* const* d_in, const int* in_sizes, int n_in,
                              void* d_out, int out_size, void* d_ws, size_t ws_size,
                              hipStream_t stream)
{
    const int*   doc     = (const int*)d_in[0];
    const float* emb     = (const float*)d_in[1];
    const float* diags   = (const float*)d_in[2];
    const float* bias    = (const float*)d_in[3];
    const float* epsilon = (const float*)d_in[4];
    const float* w0      = (const float*)d_in[5];
    const float* b0      = (const float*)d_in[6];
    const float* w1      = (const float*)d_in[7];
    const float* b1      = (const float*)d_in[8];
    const float* w2      = (const float*)d_in[9];
    const float* b2      = (const float*)d_in[10];
    float* out = (float*)d_out;

    // Workspace (~42.7 MB)
    float* G1     = (float*)d_ws;                       // NCH*49*256 fp32 (12.85 MB)
    float* scores = G1 + (size_t)NCH * 49 * P_;         // 256 floats
    int*   bar    = (int*)(scores + P_);                // 2 ints (+pad to 16B)
    __hip_bfloat16* Tb = (__hip_bfloat16*)(bar + 4);    // N_*J_ bf16 (25.2 MB)
    __hip_bfloat16* X  = Tb + (size_t)N_ * J_;          // N_*KP bf16 ( 2.6 MB)
    __hip_bfloat16* Bb = X  + (size_t)N_ * KP;          // J_*KP bf16 ( 2.0 MB)

    prep_XB<<<(N_ * KP + J_ * KP) / 256, 256, 0, stream>>>(doc, emb, diags, X, Bb, bar);
    gemm_mfma<<<(J_ / 128) * (N_ / 128), 256, 0, stream>>>(X, Bb, bias, Tb);
    tail_all<<<NBLK, 256, 0, stream>>>(Tb, epsilon, G1, scores, bar,
                                       w0, b0, w1, b1, w2, b2, out);
}

// Round 10
// 66.026 us; speedup vs baseline: 4.0962x; 1.6722x over previous
//
#include <hip/hip_runtime.h>
#include <hip/hip_bf16.h>
#include <cstdint>
#include <cstddef>

#define P_ 256
#define L_ 6
#define D_ 300
#define J_ 3072   // P*2*L
#define N_ 4096
#define H_ 256
#define C_ 5
#define KP 320    // K padded to multiple of 32
#define KSTEPS 10 // KP/32

#define SLS 0.62245933120185459f  // sigmoid(0.5)

typedef __attribute__((ext_vector_type(8))) short short8v;  // 8 bf16
typedef __attribute__((ext_vector_type(4))) short short4v;  // 4 bf16 (8B)
typedef __attribute__((ext_vector_type(4))) float f32x4;

__device__ __forceinline__ float sigmoidf_(float x) { return 1.0f / (1.0f + __expf(-x)); }
__device__ __forceinline__ float bf2f(short s) { return __uint_as_float(((unsigned)(unsigned short)s) << 16); }

// ---------------------------------------------------------------------------
// Kernel 1: gather emb[doc] -> X bf16 [N_][KP]; diags -> Bb bf16 [J_][KP].
// ---------------------------------------------------------------------------
__global__ __launch_bounds__(256) void prep_XB(
    const int* __restrict__ doc, const float* __restrict__ emb,
    const float* __restrict__ diags,
    __hip_bfloat16* __restrict__ X, __hip_bfloat16* __restrict__ Bb)
{
    const int i = blockIdx.x * 256 + threadIdx.x;
    const int NX = N_ * KP;
    if (i < NX) {
        const int n = i / KP, k = i - n * KP;
        float v = (k < D_) ? emb[(size_t)doc[n] * D_ + k] : 0.0f;
        X[i] = __float2bfloat16(v);
    } else {
        const int ii = i - NX;
        const int j = ii / KP, k = ii - j * KP;
        float v = (k < D_) ? diags[(size_t)j * D_ + k] : 0.0f;
        Bb[ii] = __float2bfloat16(v);
    }
}

// ---------------------------------------------------------------------------
// Kernel 2: Tt = sigmoid(X @ Bb^T + bias)^T -> bf16 Tt[J_][N_] (TRANSPOSED).
// R3's validated 2-phase 128x128 MFMA core; epilogue packs the 4 accumulator
// rows (consecutive timesteps, one column j) into one 8B store at
// Tt[j*N_ + rbase] -> each j-row gets 32B-granule contiguous segments.
// ---------------------------------------------------------------------------
__global__ __launch_bounds__(256) void gemm_mfma(
    const __hip_bfloat16* __restrict__ X, const __hip_bfloat16* __restrict__ Bb,
    const float* __restrict__ bias, __hip_bfloat16* __restrict__ Tt)
{
    __shared__ __hip_bfloat16 As[2][128 * 32];
    __shared__ __hip_bfloat16 Bs[2][128 * 32];

    const int tid  = threadIdx.x;
    const int lane = tid & 63;
    const int w    = tid >> 6;          // wave 0..3
    const int wr   = w >> 1, wc = w & 1;

    // XCD-aware bijective swizzle: nwg = 768 = 8 * 96
    const int bid = blockIdx.x;
    const int swz = (bid & 7) * 96 + (bid >> 3);
    const int bx  = swz % 24, by = swz / 24;   // 24 j-tiles, 32 m-tiles
    const int m0  = by * 128;
    const int j0  = bx * 128;

    const int srow = w * 32 + (lane >> 2);   // + q*16
    const int scol = (lane & 3) * 8;

    f32x4 acc[4][4];
    #pragma unroll
    for (int m = 0; m < 4; ++m)
        #pragma unroll
        for (int n = 0; n < 4; ++n)
            acc[m][n] = (f32x4){0.f, 0.f, 0.f, 0.f};

    const int fr = lane & 15;
    const int kg = (lane >> 4) * 8;

    auto stage = [&](int kt, int b) {
        const int k0 = kt * 32;
        #pragma unroll
        for (int q = 0; q < 2; ++q) {
            const __hip_bfloat16* ga = X + (size_t)(m0 + srow + q * 16) * KP + k0 + scol;
            __builtin_amdgcn_global_load_lds(
                (const __attribute__((address_space(1))) unsigned*)ga,
                (__attribute__((address_space(3))) unsigned*)(&As[b][(w * 2 + q) * 512]),
                16, 0, 0);
            const __hip_bfloat16* gb = Bb + (size_t)(j0 + srow + q * 16) * KP + k0 + scol;
            __builtin_amdgcn_global_load_lds(
                (const __attribute__((address_space(1))) unsigned*)gb,
                (__attribute__((address_space(3))) unsigned*)(&Bs[b][(w * 2 + q) * 512]),
                16, 0, 0);
        }
    };

    stage(0, 0);
    __syncthreads();

    int buf = 0;
    for (int kt = 0; kt < KSTEPS; ++kt) {
        if (kt + 1 < KSTEPS) stage(kt + 1, buf ^ 1);

        short8v a[4], b[4];
        #pragma unroll
        for (int m = 0; m < 4; ++m)
            a[m] = *(const short8v*)(&As[buf][(wr * 64 + m * 16 + fr) * 32 + kg]);
        #pragma unroll
        for (int n = 0; n < 4; ++n)
            b[n] = *(const short8v*)(&Bs[buf][(wc * 64 + n * 16 + fr) * 32 + kg]);
        #pragma unroll
        for (int m = 0; m < 4; ++m)
            #pragma unroll
            for (int n = 0; n < 4; ++n)
                acc[m][n] = __builtin_amdgcn_mfma_f32_16x16x32_bf16(a[m], b[n], acc[m][n], 0, 0, 0);

        __syncthreads();
        buf ^= 1;
    }

    // epilogue: C/D mapping col=lane&15, row=(lane>>4)*4+reg  [m89-verified]
    #pragma unroll
    for (int n = 0; n < 4; ++n) {
        const int j = j0 + wc * 64 + n * 16 + fr;
        const float bj = bias[j];
        #pragma unroll
        for (int m = 0; m < 4; ++m) {
            const int rbase = m0 + wr * 64 + m * 16 + (lane >> 4) * 4;
            short4v pk;
            #pragma unroll
            for (int r = 0; r < 4; ++r) {
                float v = acc[m][n][r] + bj;
                __hip_bfloat16 hb = __float2bfloat16(sigmoidf_(v));
                pk[r] = *reinterpret_cast<const short*>(&hb);
            }
            *(short4v*)(Tt + (size_t)j * N_ + rbase) = pk;
        }
    }
}

// ---------------------------------------------------------------------------
// Affine-map compose: N = C o R (apply R first, then C). Flat q = j*7+i.
// ---------------------------------------------------------------------------
__device__ __forceinline__ void compose_maps(const float* C, const float* R, float* N)
{
    #pragma unroll
    for (int j = 0; j < 7; ++j) {
        #pragma unroll
        for (int i = 0; i < 6; ++i) {
            float a = (j == 6) ? C[42 + i] : 0.0f;
            #pragma unroll
            for (int u = 0; u < 6; ++u) a = fmaf(C[u * 7 + i], R[j * 7 + u], a);
            N[j * 7 + i] = a;
        }
        float sa = R[j * 7 + 6] + ((j == 6) ? C[48] : 0.0f);
        #pragma unroll
        for (int u = 0; u < 6; ++u) sa = fmaf(C[u * 7 + 6], R[j * 7 + u], sa);
        N[j * 7 + 6] = sa;
    }
}

// ---------------------------------------------------------------------------
// Kernel 3 (block = PATTERN, fully block-local — NO cross-block sync):
//  P1: thread c computes chunk c's map (16 steps) from Tt (coalesced) -> LDS.
//  P2: in-LDS binary tree (8 levels) -> scores[p]. No global intermediate.
// ---------------------------------------------------------------------------
__global__ __launch_bounds__(256) void scan_tree(
    const __hip_bfloat16* __restrict__ Tt, const float* __restrict__ epsilon,
    float* __restrict__ scores)
{
    __shared__ float lds[256 * 49];   // 50176 B
    const int tid = threadIdx.x;
    const int p   = blockIdx.x;       // pattern

    // ---------------- P1: chunk map (thread = chunk c, 16 steps) -----------
    {
        const int c = tid;
        float ep[5];
        #pragma unroll
        for (int l = 0; l < 5; ++l)
            ep[l] = SLS * (1.0f / (1.0f + __expf(-epsilon[p * 5 + l])));

        float hc[7][6], sc[7];
        #pragma unroll
        for (int j = 0; j < 7; ++j) {
            sc[j] = 0.0f;
            #pragma unroll
            for (int i = 0; i < 6; ++i) hc[j][i] = (i == j) ? 1.0f : 0.0f;
        }

        #pragma unroll
        for (int h = 0; h < 2; ++h) {
            short8v v[12];
            #pragma unroll
            for (int l = 0; l < 12; ++l)
                v[l] = *(const short8v*)(Tt + (size_t)(p * 12 + l) * N_ + c * 16 + h * 8);

            #pragma unroll
            for (int tt = 0; tt < 8; ++tt) {
                float sT0[6], T1v[6];
                #pragma unroll
                for (int l = 0; l < 6; ++l) {
                    sT0[l] = SLS * bf2f(v[l][tt]);
                    T1v[l] = bf2f(v[6 + l][tt]);
                }
                #pragma unroll
                for (int j = 0; j < 7; ++j) {
                    float m[6];
                    m[0] = hc[j][0] * sT0[0];
                    #pragma unroll
                    for (int i = 1; i < 6; ++i)
                        m[i] = fmaf(hc[j][i - 1], T1v[i - 1], hc[j][i] * sT0[i]);
                    hc[j][0] = m[0] + ((j == 6) ? 1.0f : 0.0f);
                    #pragma unroll
                    for (int i = 1; i < 6; ++i)
                        hc[j][i] = fmaf(m[i - 1], ep[i - 1], m[i]);
                    sc[j] += hc[j][5];
                }
            }
        }

        #pragma unroll
        for (int j = 0; j < 7; ++j) {
            #pragma unroll
            for (int i = 0; i < 6; ++i) lds[c * 49 + j * 7 + i] = hc[j][i];
            lds[c * 49 + j * 7 + 6] = sc[j];
        }
    }

    // ---------------- P2: in-LDS binary tree over 256 chunk maps -----------
    for (int act = 128; act >= 1; act >>= 1) {
        __syncthreads();
        float Nn[49];
        const bool on = (tid < act);
        if (on) compose_maps(&lds[(2 * tid + 1) * 49], &lds[(2 * tid) * 49], Nn);
        __syncthreads();
        if (on) {
            #pragma unroll
            for (int q = 0; q < 49; ++q) lds[tid * 49 + q] = Nn[q];
        }
    }

    // apply final map to (h0=e0, s=0): score = col0.s + col6.s
    if (tid == 0) scores[p] = lds[6] + lds[48];
}

// ---------------------------------------------------------------------------
// Kernel 4: MLP head. One block, 256 threads (validated R2/R3 pattern).
// ---------------------------------------------------------------------------
__global__ __launch_bounds__(256) void mlp_head(
    const float* __restrict__ scores,
    const float* __restrict__ w0, const float* __restrict__ b0,
    const float* __restrict__ w1, const float* __restrict__ b1,
    const float* __restrict__ w2, const float* __restrict__ b2,
    float* __restrict__ out)
{
    __shared__ float s0[H_], z0[H_], z1[H_];
    const int tid = threadIdx.x;

    s0[tid] = scores[tid];
    __syncthreads();

    float acc = b0[tid];
    {
        const float4* wr = (const float4*)(w0 + (size_t)tid * P_);
        #pragma unroll 4
        for (int q = 0; q < P_ / 4; ++q) {
            float4 w = wr[q];
            acc = fmaf(w.x, s0[q * 4 + 0], acc);
            acc = fmaf(w.y, s0[q * 4 + 1], acc);
            acc = fmaf(w.z, s0[q * 4 + 2], acc);
            acc = fmaf(w.w, s0[q * 4 + 3], acc);
        }
    }
    z0[tid] = fmaxf(acc, 0.0f);
    __syncthreads();

    acc = b1[tid];
    {
        const float4* wr = (const float4*)(w1 + (size_t)tid * H_);
        #pragma unroll 4
        for (int q = 0; q < H_ / 4; ++q) {
            float4 w = wr[q];
            acc = fmaf(w.x, z0[q * 4 + 0], acc);
            acc = fmaf(w.y, z0[q * 4 + 1], acc);
            acc = fmaf(w.z, z0[q * 4 + 2], acc);
            acc = fmaf(w.w, z0[q * 4 + 3], acc);
        }
    }
    z1[tid] = fmaxf(acc, 0.0f);
    __syncthreads();

    if (tid < C_) {
        float o = b2[tid];
        const float* wr = w2 + (size_t)tid * H_;
        for (int hh = 0; hh < H_; ++hh) o = fmaf(wr[hh], z1[hh], o);
        out[tid] = o;
    }
}

// ---------------------------------------------------------------------------
extern "C" void kernel_launch(void* const* d_in, const int* in_sizes, int n_in,
                              void* d_out, int out_size, void* d_ws, size_t ws_size,
                              hipStream_t stream)
{
    const int*   doc     = (const int*)d_in[0];
    const float* emb     = (const float*)d_in[1];
    const float* diags   = (const float*)d_in[2];
    const float* bias    = (const float*)d_in[3];
    const float* epsilon = (const float*)d_in[4];
    const float* w0      = (const float*)d_in[5];
    const float* b0      = (const float*)d_in[6];
    const float* w1      = (const float*)d_in[7];
    const float* b1      = (const float*)d_in[8];
    const float* w2      = (const float*)d_in[9];
    const float* b2      = (const float*)d_in[10];
    float* out = (float*)d_out;

    // Workspace (~30 MB): scores (1 KB), then bf16 arrays (16B-aligned).
    float* scores = (float*)d_ws;                                // 256 floats
    __hip_bfloat16* Tt = (__hip_bfloat16*)((float*)d_ws + 256);  // J_*N_ (25.2 MB)
    __hip_bfloat16* X  = Tt + (size_t)J_ * N_;                   // N_*KP ( 2.6 MB)
    __hip_bfloat16* Bb = X  + (size_t)N_ * KP;                   // J_*KP ( 2.0 MB)

    prep_XB<<<(N_ * KP + J_ * KP) / 256, 256, 0, stream>>>(doc, emb, diags, X, Bb);
    gemm_mfma<<<(J_ / 128) * (N_ / 128), 256, 0, stream>>>(X, Bb, bias, Tt);
    scan_tree<<<P_, 256, 0, stream>>>(Tt, epsilon, scores);
    mlp_head<<<1, 256, 0, stream>>>(scores, w0, b0, w1, b1, w2, b2, out);
}